// Round 1
// baseline (497.843 us; speedup 1.0000x reference)
//
#include <hip/hip_runtime.h>

#define B_ 16
#define N_ 16384
#define D_ 256
#define G_ 256
#define EPSF 1e-6f

// ---- K1: segment sums (privatized LDS) ----
#define CC 64                 // columns per block
#define NSPLIT 8              // row splits per image
#define ROWS_PER (N_/NSPLIT)  // 2048

__global__ __launch_bounds__(256) void k_segsum(const float* __restrict__ pred,
                                                const int* __restrict__ gt,
                                                float* __restrict__ sums,
                                                int* __restrict__ counts) {
    __shared__ float lsum[G_][CC];   // 64 KiB
    __shared__ int lcnt[G_];
    const int bid   = blockIdx.x;
    const int b     = bid / ((D_/CC)*NSPLIT);
    const int rest  = bid % ((D_/CC)*NSPLIT);
    const int chunk = rest / NSPLIT;
    const int split = rest % NSPLIT;
    const int c0 = chunk * CC;
    const int r0 = split * ROWS_PER;
    const int tid = threadIdx.x;

    for (int i = tid; i < G_*CC; i += 256) ((float*)lsum)[i] = 0.f;
    if (tid < G_) lcnt[tid] = 0;
    __syncthreads();

    const int ty = tid >> 4;   // 16 rows per iteration
    const int tx = tid & 15;   // 16 float4 lanes -> 64 cols
    const bool do_count = (chunk == 0) && (tx == 0);

    for (int i = 0; i < ROWS_PER; i += 16) {
        const int r = r0 + i + ty;
        const int g = gt[b*N_ + r];
        const float4 v = *(const float4*)&pred[((size_t)(b*N_ + r))*D_ + c0 + tx*4];
        atomicAdd(&lsum[g][tx*4+0], v.x);
        atomicAdd(&lsum[g][tx*4+1], v.y);
        atomicAdd(&lsum[g][tx*4+2], v.z);
        atomicAdd(&lsum[g][tx*4+3], v.w);
        if (do_count) atomicAdd(&lcnt[g], 1);
    }
    __syncthreads();

    for (int i = tid; i < G_*CC; i += 256) {
        const int g = i / CC, c = i % CC;
        atomicAdd(&sums[((size_t)(b*G_ + g))*D_ + c0 + c], lsum[g][c]);
    }
    if (chunk == 0 && tid < G_) atomicAdd(&counts[b*G_ + tid], lcnt[tid]);
}

// ---- K2: per-image tag norms, obj_num, push (via |sum of unit tags|^2) ----
__global__ __launch_bounds__(256) void k_tags(const float* __restrict__ sums,
                                              const int* __restrict__ counts,
                                              float* __restrict__ tn,
                                              float* __restrict__ pushv,
                                              float* __restrict__ objn) {
    const int b = blockIdx.x;
    const int tid = threadIdx.x;
    const int lane = tid & 63;
    const int wave = tid >> 6;
    __shared__ float s_acc[D_];
    __shared__ float red[256];

    for (int i = tid; i < D_; i += 256) s_acc[i] = 0.f;
    __syncthreads();

    const int c = lane * 4;
    float4 sl = make_float4(0.f, 0.f, 0.f, 0.f);
    for (int g = wave; g < G_; g += 4) {
        const int cnt = counts[b*G_ + g];
        const float inv = 1.0f / fmaxf((float)cnt, 1.0f);
        const float4 sm = *(const float4*)&sums[((size_t)(b*G_ + g))*D_ + c];
        const float tx = sm.x*inv, tyv = sm.y*inv, tz = sm.z*inv, tw = sm.w*inv;
        float sq = tx*tx + tyv*tyv + tz*tz + tw*tw;
        #pragma unroll
        for (int off = 32; off >= 1; off >>= 1) sq += __shfl_xor(sq, off, 64);
        const float tnorm = sqrtf(sq);
        if (lane == 0) tn[b*G_ + g] = tnorm;
        if (cnt > 0) {
            const float it = 1.0f / tnorm;   // tnorm > 0 whenever cnt > 0 (continuous data)
            sl.x += tx*it; sl.y += tyv*it; sl.z += tz*it; sl.w += tw*it;
        }
    }
    atomicAdd(&s_acc[c+0], sl.x);
    atomicAdd(&s_acc[c+1], sl.y);
    atomicAdd(&s_acc[c+2], sl.z);
    atomicAdd(&s_acc[c+3], sl.w);
    __syncthreads();

    // |s|^2 reduce
    float v = s_acc[tid];
    red[tid] = v * v;
    __syncthreads();
    for (int s = 128; s > 0; s >>= 1) {
        if (tid < s) red[tid] += red[tid + s];
        __syncthreads();
    }
    float ssq = 0.f;
    if (tid == 0) ssq = red[0];
    __syncthreads();

    // obj_num reduce
    const int cnt_t = counts[b*G_ + tid];
    red[tid] = (cnt_t > 0) ? 1.f : 0.f;
    __syncthreads();
    for (int s = 128; s > 0; s >>= 1) {
        if (tid < s) red[tid] += red[tid + s];
        __syncthreads();
    }
    if (tid == 0) {
        const float obj = red[0];
        // push_sum = obj^2 + |s|^2 - 2*obj  (includes diagonal, matches reference)
        const float push = (obj*obj - 2.f*obj + ssq) / (((obj - 1.f)*obj + EPSF) * 2.f);
        pushv[b] = push;
        objn[b] = obj;
    }
}

// ---- K3: pull pass (one wave per row) ----
#define RPB 256
__global__ __launch_bounds__(256) void k_pull(const float* __restrict__ pred,
                                              const int* __restrict__ gt,
                                              const float* __restrict__ sums,
                                              const int* __restrict__ counts,
                                              const float* __restrict__ tn,
                                              float* __restrict__ pullsum) {
    const int bid = blockIdx.x;
    const int b  = bid / (N_/RPB);
    const int r0 = (bid % (N_/RPB)) * RPB;
    const int tid = threadIdx.x;
    const int lane = tid & 63;
    const int wave = tid >> 6;
    __shared__ float lpull[G_];
    for (int i = tid; i < G_; i += 256) lpull[i] = 0.f;
    __syncthreads();

    const int c = lane * 4;
    for (int i = wave; i < RPB; i += 4) {
        const int r = r0 + i;
        const int g = gt[b*N_ + r];
        const float4 p  = *(const float4*)&pred[((size_t)(b*N_ + r))*D_ + c];
        const float4 sm = *(const float4*)&sums[((size_t)(b*G_ + g))*D_ + c];
        float dot = p.x*sm.x + p.y*sm.y + p.z*sm.z + p.w*sm.w;
        float pn  = p.x*p.x + p.y*p.y + p.z*p.z + p.w*p.w;
        #pragma unroll
        for (int off = 32; off >= 1; off >>= 1) {
            dot += __shfl_xor(dot, off, 64);
            pn  += __shfl_xor(pn,  off, 64);
        }
        if (lane == 0) {
            const int cnt = counts[b*G_ + g];
            const float inv = 1.0f / fmaxf((float)cnt, 1.0f);
            const float d = dot * inv;                       // dot(p, tag)
            const float denom = fmaxf(sqrtf(pn) * tn[b*G_ + g], EPSF);
            atomicAdd(&lpull[g], 1.0f - d/denom);
        }
    }
    __syncthreads();
    for (int i = tid; i < G_; i += 256) atomicAdd(&pullsum[b*G_ + i], lpull[i]);
}

// ---- K4: final combine ----
__global__ __launch_bounds__(256) void k_final(const float* __restrict__ pullsum,
                                               const int* __restrict__ counts,
                                               const float* __restrict__ pushv,
                                               const float* __restrict__ objn,
                                               float* __restrict__ out) {
    __shared__ float red[256];
    const int tid = threadIdx.x;
    float total = 0.f;
    for (int b = 0; b < B_; ++b) {
        const int cnt = counts[b*G_ + tid];
        const float pg = (cnt > 0) ? pullsum[b*G_ + tid] / fmaxf((float)cnt, 1.f) : 0.f;
        red[tid] = pg;
        __syncthreads();
        for (int s = 128; s > 0; s >>= 1) {
            if (tid < s) red[tid] += red[tid + s];
            __syncthreads();
        }
        if (tid == 0) {
            const float obj = objn[b];
            const float pull = red[0] / (obj + EPSF);
            const float loss = pushv[b] + pull;   // PUSH_W = PULL_W = 1
            total += (obj > 1.f) ? loss : 0.f;
        }
        __syncthreads();
    }
    if (tid == 0) out[0] = total / (float)B_;     // LOSS_W = 1
}

extern "C" void kernel_launch(void* const* d_in, const int* in_sizes, int n_in,
                              void* d_out, int out_size, void* d_ws, size_t ws_size,
                              hipStream_t stream) {
    const float* pred = (const float*)d_in[0];
    const int*   gt   = (const int*)d_in[1];
    float* out = (float*)d_out;

    char* ws = (char*)d_ws;
    const size_t SZ_SUMS = (size_t)B_*G_*D_*sizeof(float);   // 4 MiB
    const size_t SZ_CNT  = (size_t)B_*G_*sizeof(int);        // 16 KiB
    const size_t SZ_PULL = (size_t)B_*G_*sizeof(float);      // 16 KiB
    const size_t SZ_TN   = (size_t)B_*G_*sizeof(float);      // 16 KiB

    float* sums    = (float*)ws;
    int*   counts  = (int*)(ws + SZ_SUMS);
    float* pullsum = (float*)(ws + SZ_SUMS + SZ_CNT);
    float* tn      = (float*)(ws + SZ_SUMS + SZ_CNT + SZ_PULL);
    float* pushv   = (float*)(ws + SZ_SUMS + SZ_CNT + SZ_PULL + SZ_TN);
    float* objn    = pushv + B_;

    // zero the atomically-accumulated regions (sums, counts, pullsum)
    hipMemsetAsync(d_ws, 0, SZ_SUMS + SZ_CNT + SZ_PULL, stream);

    k_segsum<<<B_*(D_/CC)*NSPLIT, 256, 0, stream>>>(pred, gt, sums, counts);
    k_tags<<<B_, 256, 0, stream>>>(sums, counts, tn, pushv, objn);
    k_pull<<<B_*(N_/RPB), 256, 0, stream>>>(pred, gt, sums, counts, tn, pullsum);
    k_final<<<1, 256, 0, stream>>>(pullsum, counts, pushv, objn, out);
}

// Round 2
// 244.628 us; speedup vs baseline: 2.0351x; 2.0351x over previous
//
#include <hip/hip_runtime.h>

#define B_ 16
#define N_ 16384
#define D_ 256
#define G_ 256
#define EPSF 1e-6f
#define LCAP 61   // rows staged in LDS per (image,group) block: 61 KiB

// ---- K0: histogram (counting sort, step 1) ----
__global__ __launch_bounds__(256) void k_hist(const int* __restrict__ gt,
                                              int* __restrict__ counts) {
    __shared__ int h[G_];
    const int tid = threadIdx.x;
    h[tid] = 0;
    __syncthreads();
    const int b = blockIdx.x >> 3, s = blockIdx.x & 7;
    const int base = b*N_ + s*(N_/8);
    #pragma unroll
    for (int k = 0; k < (N_/8)/256; ++k)
        atomicAdd(&h[gt[base + k*256 + tid]], 1);
    __syncthreads();
    if (h[tid]) atomicAdd(&counts[b*G_ + tid], h[tid]);
}

// ---- K1: exclusive prefix per image (step 2) ----
__global__ __launch_bounds__(256) void k_scan(const int* __restrict__ counts,
                                              int* __restrict__ starts,
                                              int* __restrict__ cursor) {
    __shared__ int s[G_];
    const int tid = threadIdx.x, b = blockIdx.x;
    const int c = counts[b*G_ + tid];
    s[tid] = c;
    __syncthreads();
    for (int off = 1; off < G_; off <<= 1) {
        const int v = (tid >= off) ? s[tid - off] : 0;
        __syncthreads();
        s[tid] += v;
        __syncthreads();
    }
    const int st = s[tid] - c;   // exclusive
    starts[b*G_ + tid] = st;
    cursor[b*G_ + tid] = st;
}

// ---- K2: scatter row ids into group buckets (step 3) ----
__global__ __launch_bounds__(256) void k_scatter(const int* __restrict__ gt,
                                                 int* __restrict__ cursor,
                                                 int* __restrict__ sorted) {
    const int tid = threadIdx.x;
    const int b = blockIdx.x >> 3, s = blockIdx.x & 7;
    const int r0 = s*(N_/8);
    #pragma unroll
    for (int k = 0; k < (N_/8)/256; ++k) {
        const int r = r0 + k*256 + tid;
        const int g = gt[b*N_ + r];
        const int pos = atomicAdd(&cursor[b*G_ + g], 1);
        sorted[b*N_ + pos] = r;
    }
}

// ---- K3: fused gather segsum + tag norm + pull (one block per (b,g)) ----
__global__ __launch_bounds__(256) void k_fused(const float* __restrict__ pred,
                                               const int* __restrict__ sorted,
                                               const int* __restrict__ starts,
                                               const int* __restrict__ counts,
                                               float* __restrict__ sums,
                                               float* __restrict__ pull_g) {
    __shared__ float stage[LCAP][D_];   // 61 KiB
    __shared__ float sumv[D_];          // 1 KiB
    __shared__ float red4[4];
    __shared__ float pp[4];
    const int tid = threadIdx.x, lane = tid & 63, w = tid >> 6;
    const int b = blockIdx.x >> 8, g = blockIdx.x & 255;
    const int start = starts[b*G_ + g], cnt = counts[b*G_ + g];
    const int c = lane * 4;

    if (cnt == 0) {
        if (w == 0) { float4 z = make_float4(0.f,0.f,0.f,0.f);
                      *(float4*)&sums[((size_t)(b*G_+g))*D_ + c] = z; }
        if (tid == 0) pull_g[b*G_+g] = 0.f;
        return;
    }

    sumv[tid] = 0.f;
    __syncthreads();

    // lane-parallel prefetch of row ids: lane l holds iteration l's row for this wave
    int myrow = 0;
    { const int pos = w + 4*lane;
      if (pos < cnt) myrow = sorted[b*N_ + start + pos]; }

    const float* predb = pred + (size_t)b*N_*D_;
    float4 acc = make_float4(0.f,0.f,0.f,0.f);
    for (int i = w; i < cnt; i += 4) {
        const int it = (i - w) >> 2;
        const int row = (it < 64) ? __shfl(myrow, it, 64)
                                  : sorted[b*N_ + start + i];
        const float4 p = *(const float4*)&predb[(size_t)row*D_ + c];
        if (i < LCAP) *(float4*)&stage[i][c] = p;
        acc.x += p.x; acc.y += p.y; acc.z += p.z; acc.w += p.w;
    }
    atomicAdd(&sumv[c+0], acc.x);
    atomicAdd(&sumv[c+1], acc.y);
    atomicAdd(&sumv[c+2], acc.z);
    atomicAdd(&sumv[c+3], acc.w);
    __syncthreads();

    // write group sums (wave 0)
    if (w == 0) *(float4*)&sums[((size_t)(b*G_+g))*D_ + c] = *(const float4*)&sumv[c];

    // |sums|^2 block reduce
    { float v = sumv[tid];
      float sq = v * v;
      #pragma unroll
      for (int off = 32; off >= 1; off >>= 1) sq += __shfl_xor(sq, off, 64);
      if (lane == 0) red4[w] = sq; }
    __syncthreads();
    const float tnorm = sqrtf(red4[0] + red4[1] + red4[2] + red4[3]);
    const float inv = 1.0f / (float)cnt;
    const float tn_tag = tnorm * inv;               // |tag|
    const float4 s4 = *(const float4*)&sumv[c];

    float pull_acc = 0.f;
    for (int i = w; i < cnt; i += 4) {
        float4 p;
        if (i < LCAP) p = *(const float4*)&stage[i][c];
        else {
            const int row = sorted[b*N_ + start + i];
            p = *(const float4*)&predb[(size_t)row*D_ + c];
        }
        float dot = p.x*s4.x + p.y*s4.y + p.z*s4.z + p.w*s4.w;
        float pn  = p.x*p.x + p.y*p.y + p.z*p.z + p.w*p.w;
        #pragma unroll
        for (int off = 32; off >= 1; off >>= 1) {
            dot += __shfl_xor(dot, off, 64);
            pn  += __shfl_xor(pn,  off, 64);
        }
        const float denom = fmaxf(sqrtf(pn) * tn_tag, EPSF);
        pull_acc += 1.0f - (dot * inv) / denom;     // dot(p,tag) = dot(p,sums)*inv
    }
    if (lane == 0) pp[w] = pull_acc;
    __syncthreads();
    if (tid == 0) pull_g[b*G_+g] = pp[0] + pp[1] + pp[2] + pp[3];
}

// ---- K4: per-image push via |sum of unit tags|^2 ----
__global__ __launch_bounds__(256) void k_tags(const float* __restrict__ sums,
                                              const int* __restrict__ counts,
                                              float* __restrict__ pushv,
                                              float* __restrict__ objn) {
    const int b = blockIdx.x;
    const int tid = threadIdx.x;
    const int lane = tid & 63;
    const int wave = tid >> 6;
    __shared__ float s_acc[D_];
    __shared__ float red[256];

    for (int i = tid; i < D_; i += 256) s_acc[i] = 0.f;
    __syncthreads();

    const int c = lane * 4;
    float4 sl = make_float4(0.f, 0.f, 0.f, 0.f);
    for (int g = wave; g < G_; g += 4) {
        const int cnt = counts[b*G_ + g];
        const float inv = 1.0f / fmaxf((float)cnt, 1.0f);
        const float4 sm = *(const float4*)&sums[((size_t)(b*G_ + g))*D_ + c];
        const float tx = sm.x*inv, tyv = sm.y*inv, tz = sm.z*inv, tw = sm.w*inv;
        float sq = tx*tx + tyv*tyv + tz*tz + tw*tw;
        #pragma unroll
        for (int off = 32; off >= 1; off >>= 1) sq += __shfl_xor(sq, off, 64);
        if (cnt > 0) {
            const float it = 1.0f / sqrtf(sq);
            sl.x += tx*it; sl.y += tyv*it; sl.z += tz*it; sl.w += tw*it;
        }
    }
    atomicAdd(&s_acc[c+0], sl.x);
    atomicAdd(&s_acc[c+1], sl.y);
    atomicAdd(&s_acc[c+2], sl.z);
    atomicAdd(&s_acc[c+3], sl.w);
    __syncthreads();

    float v = s_acc[tid];
    red[tid] = v * v;
    __syncthreads();
    for (int s = 128; s > 0; s >>= 1) {
        if (tid < s) red[tid] += red[tid + s];
        __syncthreads();
    }
    float ssq = 0.f;
    if (tid == 0) ssq = red[0];
    __syncthreads();

    const int cnt_t = counts[b*G_ + tid];
    red[tid] = (cnt_t > 0) ? 1.f : 0.f;
    __syncthreads();
    for (int s = 128; s > 0; s >>= 1) {
        if (tid < s) red[tid] += red[tid + s];
        __syncthreads();
    }
    if (tid == 0) {
        const float obj = red[0];
        const float push = (obj*obj - 2.f*obj + ssq) / (((obj - 1.f)*obj + EPSF) * 2.f);
        pushv[b] = push;
        objn[b] = obj;
    }
}

// ---- K5: final combine ----
__global__ __launch_bounds__(256) void k_final(const float* __restrict__ pull_g,
                                               const int* __restrict__ counts,
                                               const float* __restrict__ pushv,
                                               const float* __restrict__ objn,
                                               float* __restrict__ out) {
    __shared__ float red[256];
    const int tid = threadIdx.x;
    float total = 0.f;
    for (int b = 0; b < B_; ++b) {
        const int cnt = counts[b*G_ + tid];
        const float pg = (cnt > 0) ? pull_g[b*G_ + tid] / fmaxf((float)cnt, 1.f) : 0.f;
        red[tid] = pg;
        __syncthreads();
        for (int s = 128; s > 0; s >>= 1) {
            if (tid < s) red[tid] += red[tid + s];
            __syncthreads();
        }
        if (tid == 0) {
            const float obj = objn[b];
            const float pull = red[0] / (obj + EPSF);
            const float loss = pushv[b] + pull;
            total += (obj > 1.f) ? loss : 0.f;
        }
        __syncthreads();
    }
    if (tid == 0) out[0] = total / (float)B_;
}

extern "C" void kernel_launch(void* const* d_in, const int* in_sizes, int n_in,
                              void* d_out, int out_size, void* d_ws, size_t ws_size,
                              hipStream_t stream) {
    const float* pred = (const float*)d_in[0];
    const int*   gt   = (const int*)d_in[1];
    float* out = (float*)d_out;

    char* ws = (char*)d_ws;
    const size_t SZ_SUMS = (size_t)B_*G_*D_*sizeof(float);   // 4 MiB
    const size_t SZ_I    = (size_t)B_*G_*sizeof(int);        // 16 KiB each

    float* sums    = (float*)ws;                               ws += SZ_SUMS;
    int*   counts  = (int*)ws;                                 ws += SZ_I;
    int*   starts  = (int*)ws;                                 ws += SZ_I;
    int*   cursor  = (int*)ws;                                 ws += SZ_I;
    float* pull_g  = (float*)ws;                               ws += SZ_I;
    float* pushv   = (float*)ws;                               ws += 64;
    float* objn    = (float*)ws;                               ws += 64;
    int*   sorted  = (int*)ws;                                 // B*N ints = 1 MiB

    hipMemsetAsync(counts, 0, SZ_I, stream);

    k_hist   <<<B_*8,  256, 0, stream>>>(gt, counts);
    k_scan   <<<B_,    256, 0, stream>>>(counts, starts, cursor);
    k_scatter<<<B_*8,  256, 0, stream>>>(gt, cursor, sorted);
    k_fused  <<<B_*G_, 256, 0, stream>>>(pred, sorted, starts, counts, sums, pull_g);
    k_tags   <<<B_,    256, 0, stream>>>(sums, counts, pushv, objn);
    k_final  <<<1,     256, 0, stream>>>(pull_g, counts, pushv, objn, out);
}

// Round 3
// 180.436 us; speedup vs baseline: 2.7591x; 1.3558x over previous
//
#include <hip/hip_runtime.h>

#define B_ 16
#define N_ 16384
#define D_ 256
#define G_ 256
#define EPSF 1e-6f

// ---- K0: histogram (counting sort, step 1) ----
__global__ __launch_bounds__(256) void k_hist(const int* __restrict__ gt,
                                              int* __restrict__ counts) {
    __shared__ int h[G_];
    const int tid = threadIdx.x;
    h[tid] = 0;
    __syncthreads();
    const int b = blockIdx.x >> 3, s = blockIdx.x & 7;
    const int base = b*N_ + s*(N_/8);
    #pragma unroll
    for (int k = 0; k < (N_/8)/256; ++k)
        atomicAdd(&h[gt[base + k*256 + tid]], 1);
    __syncthreads();
    if (h[tid]) atomicAdd(&counts[b*G_ + tid], h[tid]);
}

// ---- K1: exclusive prefix per image (step 2) ----
__global__ __launch_bounds__(256) void k_scan(const int* __restrict__ counts,
                                              int* __restrict__ starts,
                                              int* __restrict__ cursor) {
    __shared__ int s[G_];
    const int tid = threadIdx.x, b = blockIdx.x;
    const int c = counts[b*G_ + tid];
    s[tid] = c;
    __syncthreads();
    for (int off = 1; off < G_; off <<= 1) {
        const int v = (tid >= off) ? s[tid - off] : 0;
        __syncthreads();
        s[tid] += v;
        __syncthreads();
    }
    const int st = s[tid] - c;   // exclusive
    starts[b*G_ + tid] = st;
    cursor[b*G_ + tid] = st;
}

// ---- K2: scatter row ids into group buckets (step 3) ----
__global__ __launch_bounds__(256) void k_scatter(const int* __restrict__ gt,
                                                 int* __restrict__ cursor,
                                                 int* __restrict__ sorted) {
    const int tid = threadIdx.x;
    const int b = blockIdx.x >> 3, s = blockIdx.x & 7;
    const int r0 = s*(N_/8);
    #pragma unroll
    for (int k = 0; k < (N_/8)/256; ++k) {
        const int r = r0 + k*256 + tid;
        const int g = gt[b*N_ + r];
        const int pos = atomicAdd(&cursor[b*G_ + g], 1);
        sorted[b*N_ + pos] = r;
    }
}

// ---- K3: fused gather segsum + tag norm + pull (one block per (b,g)) ----
// No LDS row staging: phase 2 re-reads rows from global (L2/L3-hot, the block
// just touched them in phase 1). LDS ~1.1 KB -> ~5 blocks/CU (VGPR-limited).
__global__ __launch_bounds__(256) void k_fused(const float* __restrict__ pred,
                                               const int* __restrict__ sorted,
                                               const int* __restrict__ starts,
                                               const int* __restrict__ counts,
                                               float* __restrict__ sums,
                                               float* __restrict__ pull_g) {
    __shared__ float sumv[D_];          // 1 KiB
    __shared__ float red4[4];
    __shared__ float pp[4];
    const int tid = threadIdx.x, lane = tid & 63, w = tid >> 6;
    const int b = blockIdx.x >> 8, g = blockIdx.x & 255;
    const int start = starts[b*G_ + g], cnt = counts[b*G_ + g];
    const int c = lane * 4;

    if (cnt == 0) {
        if (w == 0) { float4 z = make_float4(0.f,0.f,0.f,0.f);
                      *(float4*)&sums[((size_t)(b*G_+g))*D_ + c] = z; }
        if (tid == 0) pull_g[b*G_+g] = 0.f;
        return;
    }

    sumv[tid] = 0.f;
    __syncthreads();

    // lane-parallel prefetch of row ids: lane l holds iteration l's row for this wave
    int myrow = 0;
    { const int pos = w + 4*lane;
      if (pos < cnt) myrow = sorted[b*N_ + start + pos]; }

    const float* predb = pred + (size_t)b*N_*D_;

    // ---- phase 1: segment sum (unroll x2: two 1KiB row loads in flight) ----
    float4 acc = make_float4(0.f,0.f,0.f,0.f);
    int i = w;
    for (; i + 4 < cnt; i += 8) {
        const int it0 = (i - w) >> 2;
        const int it1 = it0 + 1;
        const int row0 = (it0 < 64) ? __shfl(myrow, it0, 64) : sorted[b*N_ + start + i];
        const int row1 = (it1 < 64) ? __shfl(myrow, it1, 64) : sorted[b*N_ + start + i + 4];
        const float4 p0 = *(const float4*)&predb[(size_t)row0*D_ + c];
        const float4 p1 = *(const float4*)&predb[(size_t)row1*D_ + c];
        acc.x += p0.x + p1.x; acc.y += p0.y + p1.y;
        acc.z += p0.z + p1.z; acc.w += p0.w + p1.w;
    }
    if (i < cnt) {
        const int it0 = (i - w) >> 2;
        const int row0 = (it0 < 64) ? __shfl(myrow, it0, 64) : sorted[b*N_ + start + i];
        const float4 p0 = *(const float4*)&predb[(size_t)row0*D_ + c];
        acc.x += p0.x; acc.y += p0.y; acc.z += p0.z; acc.w += p0.w;
    }
    atomicAdd(&sumv[c+0], acc.x);
    atomicAdd(&sumv[c+1], acc.y);
    atomicAdd(&sumv[c+2], acc.z);
    atomicAdd(&sumv[c+3], acc.w);
    __syncthreads();

    // write group sums (wave 0)
    if (w == 0) *(float4*)&sums[((size_t)(b*G_+g))*D_ + c] = *(const float4*)&sumv[c];

    // |sums|^2 block reduce
    { float v = sumv[tid];
      float sq = v * v;
      #pragma unroll
      for (int off = 32; off >= 1; off >>= 1) sq += __shfl_xor(sq, off, 64);
      if (lane == 0) red4[w] = sq; }
    __syncthreads();
    const float tnorm = sqrtf(red4[0] + red4[1] + red4[2] + red4[3]);
    const float inv = 1.0f / (float)cnt;
    const float tn_tag = tnorm * inv;               // |tag|
    const float4 s4 = *(const float4*)&sumv[c];

    // ---- phase 2: pull (rows re-read from L2/L3; unroll x2) ----
    float pull_acc = 0.f;
    i = w;
    for (; i + 4 < cnt; i += 8) {
        const int it0 = (i - w) >> 2;
        const int it1 = it0 + 1;
        const int row0 = (it0 < 64) ? __shfl(myrow, it0, 64) : sorted[b*N_ + start + i];
        const int row1 = (it1 < 64) ? __shfl(myrow, it1, 64) : sorted[b*N_ + start + i + 4];
        const float4 p0 = *(const float4*)&predb[(size_t)row0*D_ + c];
        const float4 p1 = *(const float4*)&predb[(size_t)row1*D_ + c];
        float d0 = p0.x*s4.x + p0.y*s4.y + p0.z*s4.z + p0.w*s4.w;
        float n0 = p0.x*p0.x + p0.y*p0.y + p0.z*p0.z + p0.w*p0.w;
        float d1 = p1.x*s4.x + p1.y*s4.y + p1.z*s4.z + p1.w*s4.w;
        float n1 = p1.x*p1.x + p1.y*p1.y + p1.z*p1.z + p1.w*p1.w;
        #pragma unroll
        for (int off = 32; off >= 1; off >>= 1) {
            d0 += __shfl_xor(d0, off, 64);
            n0 += __shfl_xor(n0, off, 64);
            d1 += __shfl_xor(d1, off, 64);
            n1 += __shfl_xor(n1, off, 64);
        }
        const float den0 = fmaxf(sqrtf(n0) * tn_tag, EPSF);
        const float den1 = fmaxf(sqrtf(n1) * tn_tag, EPSF);
        pull_acc += 2.0f - (d0 * inv) / den0 - (d1 * inv) / den1;
    }
    if (i < cnt) {
        const int it0 = (i - w) >> 2;
        const int row0 = (it0 < 64) ? __shfl(myrow, it0, 64) : sorted[b*N_ + start + i];
        const float4 p0 = *(const float4*)&predb[(size_t)row0*D_ + c];
        float d0 = p0.x*s4.x + p0.y*s4.y + p0.z*s4.z + p0.w*s4.w;
        float n0 = p0.x*p0.x + p0.y*p0.y + p0.z*p0.z + p0.w*p0.w;
        #pragma unroll
        for (int off = 32; off >= 1; off >>= 1) {
            d0 += __shfl_xor(d0, off, 64);
            n0 += __shfl_xor(n0, off, 64);
        }
        const float den0 = fmaxf(sqrtf(n0) * tn_tag, EPSF);
        pull_acc += 1.0f - (d0 * inv) / den0;
    }
    if (lane == 0) pp[w] = pull_acc;
    __syncthreads();
    if (tid == 0) pull_g[b*G_+g] = pp[0] + pp[1] + pp[2] + pp[3];
}

// ---- K4: per-image push via |sum of unit tags|^2 ----
__global__ __launch_bounds__(256) void k_tags(const float* __restrict__ sums,
                                              const int* __restrict__ counts,
                                              float* __restrict__ pushv,
                                              float* __restrict__ objn) {
    const int b = blockIdx.x;
    const int tid = threadIdx.x;
    const int lane = tid & 63;
    const int wave = tid >> 6;
    __shared__ float s_acc[D_];
    __shared__ float red[256];

    for (int i = tid; i < D_; i += 256) s_acc[i] = 0.f;
    __syncthreads();

    const int c = lane * 4;
    float4 sl = make_float4(0.f, 0.f, 0.f, 0.f);
    for (int g = wave; g < G_; g += 4) {
        const int cnt = counts[b*G_ + g];
        const float inv = 1.0f / fmaxf((float)cnt, 1.0f);
        const float4 sm = *(const float4*)&sums[((size_t)(b*G_ + g))*D_ + c];
        const float tx = sm.x*inv, tyv = sm.y*inv, tz = sm.z*inv, tw = sm.w*inv;
        float sq = tx*tx + tyv*tyv + tz*tz + tw*tw;
        #pragma unroll
        for (int off = 32; off >= 1; off >>= 1) sq += __shfl_xor(sq, off, 64);
        if (cnt > 0) {
            const float it = 1.0f / sqrtf(sq);
            sl.x += tx*it; sl.y += tyv*it; sl.z += tz*it; sl.w += tw*it;
        }
    }
    atomicAdd(&s_acc[c+0], sl.x);
    atomicAdd(&s_acc[c+1], sl.y);
    atomicAdd(&s_acc[c+2], sl.z);
    atomicAdd(&s_acc[c+3], sl.w);
    __syncthreads();

    float v = s_acc[tid];
    red[tid] = v * v;
    __syncthreads();
    for (int s = 128; s > 0; s >>= 1) {
        if (tid < s) red[tid] += red[tid + s];
        __syncthreads();
    }
    float ssq = 0.f;
    if (tid == 0) ssq = red[0];
    __syncthreads();

    const int cnt_t = counts[b*G_ + tid];
    red[tid] = (cnt_t > 0) ? 1.f : 0.f;
    __syncthreads();
    for (int s = 128; s > 0; s >>= 1) {
        if (tid < s) red[tid] += red[tid + s];
        __syncthreads();
    }
    if (tid == 0) {
        const float obj = red[0];
        const float push = (obj*obj - 2.f*obj + ssq) / (((obj - 1.f)*obj + EPSF) * 2.f);
        pushv[b] = push;
        objn[b] = obj;
    }
}

// ---- K5: final combine ----
__global__ __launch_bounds__(256) void k_final(const float* __restrict__ pull_g,
                                               const int* __restrict__ counts,
                                               const float* __restrict__ pushv,
                                               const float* __restrict__ objn,
                                               float* __restrict__ out) {
    __shared__ float red[256];
    const int tid = threadIdx.x;
    float total = 0.f;
    for (int b = 0; b < B_; ++b) {
        const int cnt = counts[b*G_ + tid];
        const float pg = (cnt > 0) ? pull_g[b*G_ + tid] / fmaxf((float)cnt, 1.f) : 0.f;
        red[tid] = pg;
        __syncthreads();
        for (int s = 128; s > 0; s >>= 1) {
            if (tid < s) red[tid] += red[tid + s];
            __syncthreads();
        }
        if (tid == 0) {
            const float obj = objn[b];
            const float pull = red[0] / (obj + EPSF);
            const float loss = pushv[b] + pull;
            total += (obj > 1.f) ? loss : 0.f;
        }
        __syncthreads();
    }
    if (tid == 0) out[0] = total / (float)B_;
}

extern "C" void kernel_launch(void* const* d_in, const int* in_sizes, int n_in,
                              void* d_out, int out_size, void* d_ws, size_t ws_size,
                              hipStream_t stream) {
    const float* pred = (const float*)d_in[0];
    const int*   gt   = (const int*)d_in[1];
    float* out = (float*)d_out;

    char* ws = (char*)d_ws;
    const size_t SZ_SUMS = (size_t)B_*G_*D_*sizeof(float);   // 4 MiB
    const size_t SZ_I    = (size_t)B_*G_*sizeof(int);        // 16 KiB each

    float* sums    = (float*)ws;                               ws += SZ_SUMS;
    int*   counts  = (int*)ws;                                 ws += SZ_I;
    int*   starts  = (int*)ws;                                 ws += SZ_I;
    int*   cursor  = (int*)ws;                                 ws += SZ_I;
    float* pull_g  = (float*)ws;                               ws += SZ_I;
    float* pushv   = (float*)ws;                               ws += 64;
    float* objn    = (float*)ws;                               ws += 64;
    int*   sorted  = (int*)ws;                                 // B*N ints = 1 MiB

    hipMemsetAsync(counts, 0, SZ_I, stream);

    k_hist   <<<B_*8,  256, 0, stream>>>(gt, counts);
    k_scan   <<<B_,    256, 0, stream>>>(counts, starts, cursor);
    k_scatter<<<B_*8,  256, 0, stream>>>(gt, cursor, sorted);
    k_fused  <<<B_*G_, 256, 0, stream>>>(pred, sorted, starts, counts, sums, pull_g);
    k_tags   <<<B_,    256, 0, stream>>>(sums, counts, pushv, objn);
    k_final  <<<1,     256, 0, stream>>>(pull_g, counts, pushv, objn, out);
}

// Round 4
// 165.872 us; speedup vs baseline: 3.0014x; 1.0878x over previous
//
#include <hip/hip_runtime.h>

#define B_ 16
#define N_ 16384
#define D_ 256
#define G_ 256
#define EPSF 1e-6f

// ---- K0: histogram (counting sort, step 1) ----
__global__ __launch_bounds__(256) void k_hist(const int* __restrict__ gt,
                                              int* __restrict__ counts) {
    __shared__ int h[G_];
    const int tid = threadIdx.x;
    h[tid] = 0;
    __syncthreads();
    const int b = blockIdx.x >> 3, s = blockIdx.x & 7;
    const int base = b*N_ + s*(N_/8);
    #pragma unroll
    for (int k = 0; k < (N_/8)/256; ++k)
        atomicAdd(&h[gt[base + k*256 + tid]], 1);
    __syncthreads();
    if (h[tid]) atomicAdd(&counts[b*G_ + tid], h[tid]);
}

// ---- K1: exclusive prefix per image (step 2) ----
__global__ __launch_bounds__(256) void k_scan(const int* __restrict__ counts,
                                              int* __restrict__ starts,
                                              int* __restrict__ cursor) {
    __shared__ int s[G_];
    const int tid = threadIdx.x, b = blockIdx.x;
    const int c = counts[b*G_ + tid];
    s[tid] = c;
    __syncthreads();
    for (int off = 1; off < G_; off <<= 1) {
        const int v = (tid >= off) ? s[tid - off] : 0;
        __syncthreads();
        s[tid] += v;
        __syncthreads();
    }
    const int st = s[tid] - c;   // exclusive
    starts[b*G_ + tid] = st;
    cursor[b*G_ + tid] = st;
}

// ---- K2: scatter row ids into group buckets (step 3) ----
__global__ __launch_bounds__(256) void k_scatter(const int* __restrict__ gt,
                                                 int* __restrict__ cursor,
                                                 int* __restrict__ sorted) {
    const int tid = threadIdx.x;
    const int b = blockIdx.x >> 3, s = blockIdx.x & 7;
    const int r0 = s*(N_/8);
    #pragma unroll
    for (int k = 0; k < (N_/8)/256; ++k) {
        const int r = r0 + k*256 + tid;
        const int g = gt[b*N_ + r];
        const int pos = atomicAdd(&cursor[b*G_ + g], 1);
        sorted[b*N_ + pos] = r;
    }
}

// ---- K3: single-pass fused kernel (one block per (b,g)) ----
// Reads each group's rows ONCE. Accumulates S = sum(p) and U = sum(p/|p|)
// in registers; per-row |p| via 6-level shuffle reduce.
// pull_g = cnt - dot(U,S)/|S|   (EPS clamp never fires for this data).
__global__ __launch_bounds__(256) void k_fused(const float* __restrict__ pred,
                                               const int* __restrict__ sorted,
                                               const int* __restrict__ starts,
                                               const int* __restrict__ counts,
                                               float* __restrict__ sums,
                                               float* __restrict__ pull_g) {
    __shared__ float sumv[D_];   // 1 KiB
    __shared__ float usum[D_];   // 1 KiB
    __shared__ float redS[4], redU[4];
    const int tid = threadIdx.x, lane = tid & 63, w = tid >> 6;
    const int b = blockIdx.x >> 8, g = blockIdx.x & 255;
    const int start = starts[b*G_ + g], cnt = counts[b*G_ + g];
    const int c = lane * 4;

    if (cnt == 0) {
        if (w == 0) { float4 z = make_float4(0.f,0.f,0.f,0.f);
                      *(float4*)&sums[((size_t)(b*G_+g))*D_ + c] = z; }
        if (tid == 0) pull_g[b*G_+g] = 0.f;
        return;
    }

    sumv[tid] = 0.f;
    usum[tid] = 0.f;
    __syncthreads();

    // lane-parallel prefetch of row ids: lane l holds iteration l's row for this wave
    int myrow = 0;
    { const int pos = w + 4*lane;
      if (pos < cnt) myrow = sorted[b*N_ + start + pos]; }

    const float* predb = pred + (size_t)b*N_*D_;

    float4 acc  = make_float4(0.f,0.f,0.f,0.f);   // sum(p)
    float4 uacc = make_float4(0.f,0.f,0.f,0.f);   // sum(p/|p|)
    int i = w;
    for (; i + 4 < cnt; i += 8) {
        const int it0 = (i - w) >> 2;
        const int it1 = it0 + 1;
        const int row0 = (it0 < 64) ? __shfl(myrow, it0, 64) : sorted[b*N_ + start + i];
        const int row1 = (it1 < 64) ? __shfl(myrow, it1, 64) : sorted[b*N_ + start + i + 4];
        const float4 p0 = *(const float4*)&predb[(size_t)row0*D_ + c];
        const float4 p1 = *(const float4*)&predb[(size_t)row1*D_ + c];
        float n0 = p0.x*p0.x + p0.y*p0.y + p0.z*p0.z + p0.w*p0.w;
        float n1 = p1.x*p1.x + p1.y*p1.y + p1.z*p1.z + p1.w*p1.w;
        #pragma unroll
        for (int off = 32; off >= 1; off >>= 1) {
            n0 += __shfl_xor(n0, off, 64);
            n1 += __shfl_xor(n1, off, 64);
        }
        const float r0 = 1.0f / sqrtf(n0);
        const float r1 = 1.0f / sqrtf(n1);
        acc.x  += p0.x + p1.x;      acc.y  += p0.y + p1.y;
        acc.z  += p0.z + p1.z;      acc.w  += p0.w + p1.w;
        uacc.x += p0.x*r0 + p1.x*r1; uacc.y += p0.y*r0 + p1.y*r1;
        uacc.z += p0.z*r0 + p1.z*r1; uacc.w += p0.w*r0 + p1.w*r1;
    }
    if (i < cnt) {
        const int it0 = (i - w) >> 2;
        const int row0 = (it0 < 64) ? __shfl(myrow, it0, 64) : sorted[b*N_ + start + i];
        const float4 p0 = *(const float4*)&predb[(size_t)row0*D_ + c];
        float n0 = p0.x*p0.x + p0.y*p0.y + p0.z*p0.z + p0.w*p0.w;
        #pragma unroll
        for (int off = 32; off >= 1; off >>= 1) n0 += __shfl_xor(n0, off, 64);
        const float r0 = 1.0f / sqrtf(n0);
        acc.x  += p0.x;    acc.y  += p0.y;    acc.z  += p0.z;    acc.w  += p0.w;
        uacc.x += p0.x*r0; uacc.y += p0.y*r0; uacc.z += p0.z*r0; uacc.w += p0.w*r0;
    }
    atomicAdd(&sumv[c+0], acc.x);
    atomicAdd(&sumv[c+1], acc.y);
    atomicAdd(&sumv[c+2], acc.z);
    atomicAdd(&sumv[c+3], acc.w);
    atomicAdd(&usum[c+0], uacc.x);
    atomicAdd(&usum[c+1], uacc.y);
    atomicAdd(&usum[c+2], uacc.z);
    atomicAdd(&usum[c+3], uacc.w);
    __syncthreads();

    // write group sums (wave 0) for the push kernel
    if (w == 0) *(float4*)&sums[((size_t)(b*G_+g))*D_ + c] = *(const float4*)&sumv[c];

    // |S|^2 and dot(U,S) block reduces
    { const float s = sumv[tid], u = usum[tid];
      float sq = s * s, du = u * s;
      #pragma unroll
      for (int off = 32; off >= 1; off >>= 1) {
          sq += __shfl_xor(sq, off, 64);
          du += __shfl_xor(du, off, 64);
      }
      if (lane == 0) { redS[w] = sq; redU[w] = du; } }
    __syncthreads();
    if (tid == 0) {
        const float Ssq   = redS[0] + redS[1] + redS[2] + redS[3];
        const float dotUS = redU[0] + redU[1] + redU[2] + redU[3];
        pull_g[b*G_+g] = (float)cnt - dotUS / sqrtf(Ssq);
    }
}

// ---- K4: per-image push via |sum of unit tags|^2 ----
__global__ __launch_bounds__(256) void k_tags(const float* __restrict__ sums,
                                              const int* __restrict__ counts,
                                              float* __restrict__ pushv,
                                              float* __restrict__ objn) {
    const int b = blockIdx.x;
    const int tid = threadIdx.x;
    const int lane = tid & 63;
    const int wave = tid >> 6;
    __shared__ float s_acc[D_];
    __shared__ float red[256];

    for (int i = tid; i < D_; i += 256) s_acc[i] = 0.f;
    __syncthreads();

    const int c = lane * 4;
    float4 sl = make_float4(0.f, 0.f, 0.f, 0.f);
    for (int g = wave; g < G_; g += 4) {
        const int cnt = counts[b*G_ + g];
        const float inv = 1.0f / fmaxf((float)cnt, 1.0f);
        const float4 sm = *(const float4*)&sums[((size_t)(b*G_ + g))*D_ + c];
        const float tx = sm.x*inv, tyv = sm.y*inv, tz = sm.z*inv, tw = sm.w*inv;
        float sq = tx*tx + tyv*tyv + tz*tz + tw*tw;
        #pragma unroll
        for (int off = 32; off >= 1; off >>= 1) sq += __shfl_xor(sq, off, 64);
        if (cnt > 0) {
            const float it = 1.0f / sqrtf(sq);
            sl.x += tx*it; sl.y += tyv*it; sl.z += tz*it; sl.w += tw*it;
        }
    }
    atomicAdd(&s_acc[c+0], sl.x);
    atomicAdd(&s_acc[c+1], sl.y);
    atomicAdd(&s_acc[c+2], sl.z);
    atomicAdd(&s_acc[c+3], sl.w);
    __syncthreads();

    float v = s_acc[tid];
    red[tid] = v * v;
    __syncthreads();
    for (int s = 128; s > 0; s >>= 1) {
        if (tid < s) red[tid] += red[tid + s];
        __syncthreads();
    }
    float ssq = 0.f;
    if (tid == 0) ssq = red[0];
    __syncthreads();

    const int cnt_t = counts[b*G_ + tid];
    red[tid] = (cnt_t > 0) ? 1.f : 0.f;
    __syncthreads();
    for (int s = 128; s > 0; s >>= 1) {
        if (tid < s) red[tid] += red[tid + s];
        __syncthreads();
    }
    if (tid == 0) {
        const float obj = red[0];
        const float push = (obj*obj - 2.f*obj + ssq) / (((obj - 1.f)*obj + EPSF) * 2.f);
        pushv[b] = push;
        objn[b] = obj;
    }
}

// ---- K5: final combine ----
__global__ __launch_bounds__(256) void k_final(const float* __restrict__ pull_g,
                                               const int* __restrict__ counts,
                                               const float* __restrict__ pushv,
                                               const float* __restrict__ objn,
                                               float* __restrict__ out) {
    __shared__ float red[256];
    const int tid = threadIdx.x;
    float total = 0.f;
    for (int b = 0; b < B_; ++b) {
        const int cnt = counts[b*G_ + tid];
        const float pg = (cnt > 0) ? pull_g[b*G_ + tid] / fmaxf((float)cnt, 1.f) : 0.f;
        red[tid] = pg;
        __syncthreads();
        for (int s = 128; s > 0; s >>= 1) {
            if (tid < s) red[tid] += red[tid + s];
            __syncthreads();
        }
        if (tid == 0) {
            const float obj = objn[b];
            const float pull = red[0] / (obj + EPSF);
            const float loss = pushv[b] + pull;
            total += (obj > 1.f) ? loss : 0.f;
        }
        __syncthreads();
    }
    if (tid == 0) out[0] = total / (float)B_;
}

extern "C" void kernel_launch(void* const* d_in, const int* in_sizes, int n_in,
                              void* d_out, int out_size, void* d_ws, size_t ws_size,
                              hipStream_t stream) {
    const float* pred = (const float*)d_in[0];
    const int*   gt   = (const int*)d_in[1];
    float* out = (float*)d_out;

    char* ws = (char*)d_ws;
    const size_t SZ_SUMS = (size_t)B_*G_*D_*sizeof(float);   // 4 MiB
    const size_t SZ_I    = (size_t)B_*G_*sizeof(int);        // 16 KiB each

    float* sums    = (float*)ws;                               ws += SZ_SUMS;
    int*   counts  = (int*)ws;                                 ws += SZ_I;
    int*   starts  = (int*)ws;                                 ws += SZ_I;
    int*   cursor  = (int*)ws;                                 ws += SZ_I;
    float* pull_g  = (float*)ws;                               ws += SZ_I;
    float* pushv   = (float*)ws;                               ws += 64;
    float* objn    = (float*)ws;                               ws += 64;
    int*   sorted  = (int*)ws;                                 // B*N ints = 1 MiB

    hipMemsetAsync(counts, 0, SZ_I, stream);

    k_hist   <<<B_*8,  256, 0, stream>>>(gt, counts);
    k_scan   <<<B_,    256, 0, stream>>>(counts, starts, cursor);
    k_scatter<<<B_*8,  256, 0, stream>>>(gt, cursor, sorted);
    k_fused  <<<B_*G_, 256, 0, stream>>>(pred, sorted, starts, counts, sums, pull_g);
    k_tags   <<<B_,    256, 0, stream>>>(sums, counts, pushv, objn);
    k_final  <<<1,     256, 0, stream>>>(pull_g, counts, pushv, objn, out);
}

// Round 5
// 140.761 us; speedup vs baseline: 3.5368x; 1.1784x over previous
//
#include <hip/hip_runtime.h>

#define B_ 16
#define N_ 16384
#define D_ 256
#define G_ 256
#define EPSF 1e-6f

// ---- K0: histogram (counting sort, step 1) ----
__global__ __launch_bounds__(256) void k_hist(const int* __restrict__ gt,
                                              int* __restrict__ counts) {
    __shared__ int h[G_];
    const int tid = threadIdx.x;
    h[tid] = 0;
    __syncthreads();
    const int b = blockIdx.x >> 3, s = blockIdx.x & 7;
    const int base = b*N_ + s*(N_/8);
    #pragma unroll
    for (int k = 0; k < (N_/8)/256; ++k)
        atomicAdd(&h[gt[base + k*256 + tid]], 1);
    __syncthreads();
    if (h[tid]) atomicAdd(&counts[b*G_ + tid], h[tid]);
}

// ---- K1: exclusive prefix per image (step 2) ----
__global__ __launch_bounds__(256) void k_scan(const int* __restrict__ counts,
                                              int* __restrict__ starts,
                                              int* __restrict__ cursor) {
    __shared__ int s[G_];
    const int tid = threadIdx.x, b = blockIdx.x;
    const int c = counts[b*G_ + tid];
    s[tid] = c;
    __syncthreads();
    for (int off = 1; off < G_; off <<= 1) {
        const int v = (tid >= off) ? s[tid - off] : 0;
        __syncthreads();
        s[tid] += v;
        __syncthreads();
    }
    const int st = s[tid] - c;   // exclusive
    starts[b*G_ + tid] = st;
    cursor[b*G_ + tid] = st;
}

// ---- K2: scatter row ids into group buckets (step 3) ----
__global__ __launch_bounds__(256) void k_scatter(const int* __restrict__ gt,
                                                 int* __restrict__ cursor,
                                                 int* __restrict__ sorted) {
    const int tid = threadIdx.x;
    const int b = blockIdx.x >> 3, s = blockIdx.x & 7;
    const int r0 = s*(N_/8);
    #pragma unroll
    for (int k = 0; k < (N_/8)/256; ++k) {
        const int r = r0 + k*256 + tid;
        const int g = gt[b*N_ + r];
        const int pos = atomicAdd(&cursor[b*G_ + g], 1);
        sorted[b*N_ + pos] = r;
    }
}

// ---- K3: single-pass fused kernel (one block per (b,g)) ----
// Per group: S = sum(p), U = sum(p/|p|) in one read of the group's rows.
// pull_g = cnt - dot(U,S)/|S|.  Row ids fetched via wave-uniform scalar
// loads (readfirstlane); 4 rows in flight per wave, 4 interleaved
// butterfly chains to amortize ds_bpermute latency.
__global__ __launch_bounds__(256) void k_fused(const float* __restrict__ pred,
                                               const int* __restrict__ sorted,
                                               const int* __restrict__ starts,
                                               const int* __restrict__ counts,
                                               float* __restrict__ sums,
                                               float* __restrict__ pull_g) {
    __shared__ float sumv[D_];   // 1 KiB
    __shared__ float usum[D_];   // 1 KiB
    __shared__ float redS[4], redU[4];
    const int tid = threadIdx.x, lane = tid & 63, w = tid >> 6;
    const int b = blockIdx.x >> 8, g = blockIdx.x & 255;
    const int start = starts[b*G_ + g], cnt = counts[b*G_ + g];
    const int c = lane * 4;

    if (cnt == 0) {
        if (w == 0) { float4 z = make_float4(0.f,0.f,0.f,0.f);
                      *(float4*)&sums[((size_t)(b*G_+g))*D_ + c] = z; }
        if (tid == 0) pull_g[b*G_+g] = 0.f;
        return;
    }

    sumv[tid] = 0.f;
    usum[tid] = 0.f;
    __syncthreads();

    const float* predb = pred + (size_t)b*N_*D_;
    const int*   sortb = sorted + b*N_ + start;

    float4 acc  = make_float4(0.f,0.f,0.f,0.f);   // sum(p)
    float4 uacc = make_float4(0.f,0.f,0.f,0.f);   // sum(p/|p|)
    int i = w;

    // main loop: 4 rows per wave-iteration
    for (; i + 12 < cnt; i += 16) {
        const int r0 = sortb[__builtin_amdgcn_readfirstlane(i)];
        const int r1 = sortb[__builtin_amdgcn_readfirstlane(i + 4)];
        const int r2 = sortb[__builtin_amdgcn_readfirstlane(i + 8)];
        const int r3 = sortb[__builtin_amdgcn_readfirstlane(i + 12)];
        const float4 p0 = *(const float4*)&predb[(size_t)r0*D_ + c];
        const float4 p1 = *(const float4*)&predb[(size_t)r1*D_ + c];
        const float4 p2 = *(const float4*)&predb[(size_t)r2*D_ + c];
        const float4 p3 = *(const float4*)&predb[(size_t)r3*D_ + c];
        float n0 = p0.x*p0.x + p0.y*p0.y + p0.z*p0.z + p0.w*p0.w;
        float n1 = p1.x*p1.x + p1.y*p1.y + p1.z*p1.z + p1.w*p1.w;
        float n2 = p2.x*p2.x + p2.y*p2.y + p2.z*p2.z + p2.w*p2.w;
        float n3 = p3.x*p3.x + p3.y*p3.y + p3.z*p3.z + p3.w*p3.w;
        #pragma unroll
        for (int off = 32; off >= 1; off >>= 1) {
            n0 += __shfl_xor(n0, off, 64);
            n1 += __shfl_xor(n1, off, 64);
            n2 += __shfl_xor(n2, off, 64);
            n3 += __shfl_xor(n3, off, 64);
        }
        const float q0 = __frsqrt_rn(n0);
        const float q1 = __frsqrt_rn(n1);
        const float q2 = __frsqrt_rn(n2);
        const float q3 = __frsqrt_rn(n3);
        acc.x  += (p0.x + p1.x) + (p2.x + p3.x);
        acc.y  += (p0.y + p1.y) + (p2.y + p3.y);
        acc.z  += (p0.z + p1.z) + (p2.z + p3.z);
        acc.w  += (p0.w + p1.w) + (p2.w + p3.w);
        uacc.x += p0.x*q0 + p1.x*q1 + p2.x*q2 + p3.x*q3;
        uacc.y += p0.y*q0 + p1.y*q1 + p2.y*q2 + p3.y*q3;
        uacc.z += p0.z*q0 + p1.z*q1 + p2.z*q2 + p3.z*q3;
        uacc.w += p0.w*q0 + p1.w*q1 + p2.w*q2 + p3.w*q3;
    }
    // tail: one row at a time
    for (; i < cnt; i += 4) {
        const int r0 = sortb[__builtin_amdgcn_readfirstlane(i)];
        const float4 p0 = *(const float4*)&predb[(size_t)r0*D_ + c];
        float n0 = p0.x*p0.x + p0.y*p0.y + p0.z*p0.z + p0.w*p0.w;
        #pragma unroll
        for (int off = 32; off >= 1; off >>= 1) n0 += __shfl_xor(n0, off, 64);
        const float q0 = __frsqrt_rn(n0);
        acc.x  += p0.x;    acc.y  += p0.y;    acc.z  += p0.z;    acc.w  += p0.w;
        uacc.x += p0.x*q0; uacc.y += p0.y*q0; uacc.z += p0.z*q0; uacc.w += p0.w*q0;
    }

    atomicAdd(&sumv[c+0], acc.x);
    atomicAdd(&sumv[c+1], acc.y);
    atomicAdd(&sumv[c+2], acc.z);
    atomicAdd(&sumv[c+3], acc.w);
    atomicAdd(&usum[c+0], uacc.x);
    atomicAdd(&usum[c+1], uacc.y);
    atomicAdd(&usum[c+2], uacc.z);
    atomicAdd(&usum[c+3], uacc.w);
    __syncthreads();

    // write group sums (wave 0) for the push kernel
    if (w == 0) *(float4*)&sums[((size_t)(b*G_+g))*D_ + c] = *(const float4*)&sumv[c];

    // |S|^2 and dot(U,S) block reduces
    { const float s = sumv[tid], u = usum[tid];
      float sq = s * s, du = u * s;
      #pragma unroll
      for (int off = 32; off >= 1; off >>= 1) {
          sq += __shfl_xor(sq, off, 64);
          du += __shfl_xor(du, off, 64);
      }
      if (lane == 0) { redS[w] = sq; redU[w] = du; } }
    __syncthreads();
    if (tid == 0) {
        const float Ssq   = redS[0] + redS[1] + redS[2] + redS[3];
        const float dotUS = redU[0] + redU[1] + redU[2] + redU[3];
        pull_g[b*G_+g] = (float)cnt - dotUS / sqrtf(Ssq);
    }
}

// ---- K4: per-image push + pull combine; atomicAdd into zeroed out ----
__global__ __launch_bounds__(256) void k_tags(const float* __restrict__ sums,
                                              const int* __restrict__ counts,
                                              const float* __restrict__ pull_g,
                                              float* __restrict__ out) {
    const int b = blockIdx.x;
    const int tid = threadIdx.x;
    const int lane = tid & 63;
    const int wave = tid >> 6;
    __shared__ float s_acc[D_];
    __shared__ float redA[256];
    __shared__ float redB[256];

    for (int i = tid; i < D_; i += 256) s_acc[i] = 0.f;
    __syncthreads();

    const int c = lane * 4;
    float4 sl = make_float4(0.f, 0.f, 0.f, 0.f);
    for (int g = wave; g < G_; g += 4) {
        const int cnt = counts[b*G_ + g];
        const float inv = 1.0f / fmaxf((float)cnt, 1.0f);
        const float4 sm = *(const float4*)&sums[((size_t)(b*G_ + g))*D_ + c];
        const float tx = sm.x*inv, tyv = sm.y*inv, tz = sm.z*inv, tw = sm.w*inv;
        float sq = tx*tx + tyv*tyv + tz*tz + tw*tw;
        #pragma unroll
        for (int off = 32; off >= 1; off >>= 1) sq += __shfl_xor(sq, off, 64);
        if (cnt > 0) {
            const float it = __frsqrt_rn(sq);
            sl.x += tx*it; sl.y += tyv*it; sl.z += tz*it; sl.w += tw*it;
        }
    }
    atomicAdd(&s_acc[c+0], sl.x);
    atomicAdd(&s_acc[c+1], sl.y);
    atomicAdd(&s_acc[c+2], sl.z);
    atomicAdd(&s_acc[c+3], sl.w);
    __syncthreads();

    // redA: |sum of unit tags|^2 ; redB: obj count (then pull sum)
    const int cnt_t = counts[b*G_ + tid];
    const float v = s_acc[tid];
    redA[tid] = v * v;
    redB[tid] = (cnt_t > 0) ? 1.f : 0.f;
    __syncthreads();
    for (int s = 128; s > 0; s >>= 1) {
        if (tid < s) { redA[tid] += redA[tid + s]; redB[tid] += redB[tid + s]; }
        __syncthreads();
    }
    float ssq = 0.f, obj = 0.f;
    if (tid == 0) { ssq = redA[0]; obj = redB[0]; }
    __syncthreads();

    // pull: sum over present groups of pull_g / cnt
    redA[tid] = (cnt_t > 0) ? pull_g[b*G_ + tid] / (float)cnt_t : 0.f;
    __syncthreads();
    for (int s = 128; s > 0; s >>= 1) {
        if (tid < s) redA[tid] += redA[tid + s];
        __syncthreads();
    }
    if (tid == 0) {
        const float push = (obj*obj - 2.f*obj + ssq) / (((obj - 1.f)*obj + EPSF) * 2.f);
        const float pull = redA[0] / (obj + EPSF);
        const float loss = (obj > 1.f) ? (push + pull) : 0.f;
        atomicAdd(out, loss * (1.0f / (float)B_));
    }
}

extern "C" void kernel_launch(void* const* d_in, const int* in_sizes, int n_in,
                              void* d_out, int out_size, void* d_ws, size_t ws_size,
                              hipStream_t stream) {
    const float* pred = (const float*)d_in[0];
    const int*   gt   = (const int*)d_in[1];
    float* out = (float*)d_out;

    char* ws = (char*)d_ws;
    const size_t SZ_SUMS = (size_t)B_*G_*D_*sizeof(float);   // 4 MiB
    const size_t SZ_I    = (size_t)B_*G_*sizeof(int);        // 16 KiB each

    float* sums    = (float*)ws;                               ws += SZ_SUMS;
    int*   counts  = (int*)ws;                                 ws += SZ_I;
    int*   starts  = (int*)ws;                                 ws += SZ_I;
    int*   cursor  = (int*)ws;                                 ws += SZ_I;
    float* pull_g  = (float*)ws;                               ws += SZ_I;
    int*   sorted  = (int*)ws;                                 // B*N ints = 1 MiB

    hipMemsetAsync(counts, 0, SZ_I, stream);
    hipMemsetAsync(d_out, 0, sizeof(float), stream);

    k_hist   <<<B_*8,  256, 0, stream>>>(gt, counts);
    k_scan   <<<B_,    256, 0, stream>>>(counts, starts, cursor);
    k_scatter<<<B_*8,  256, 0, stream>>>(gt, cursor, sorted);
    k_fused  <<<B_*G_, 256, 0, stream>>>(pred, sorted, starts, counts, sums, pull_g);
    k_tags   <<<B_,    256, 0, stream>>>(sums, counts, pull_g, out);
}

// Round 6
// 139.627 us; speedup vs baseline: 3.5655x; 1.0081x over previous
//
#include <hip/hip_runtime.h>

#define B_ 16
#define N_ 16384
#define D_ 256
#define G_ 256
#define EPSF 1e-6f

// ---- DPP wave-64 sum: row_shr 1/2/4/8 + row_bcast15/31, result via readlane(63).
// VALU-pipe only (no ds_swizzle). Invalid source lanes contribute old=0.
template <int CTRL>
__device__ __forceinline__ float dpp_add_step(float x) {
    const int y = __builtin_amdgcn_update_dpp(0, __float_as_int(x), CTRL, 0xF, 0xF, false);
    return x + __int_as_float(y);
}
__device__ __forceinline__ float wave_sum64(float x) {
    x = dpp_add_step<0x111>(x);   // row_shr:1
    x = dpp_add_step<0x112>(x);   // row_shr:2
    x = dpp_add_step<0x114>(x);   // row_shr:4
    x = dpp_add_step<0x118>(x);   // row_shr:8  -> lane 15 of each row-16 has row sum
    x = dpp_add_step<0x142>(x);   // row_bcast15
    x = dpp_add_step<0x143>(x);   // row_bcast31 -> lane 63 has wave total
    return __int_as_float(__builtin_amdgcn_readlane(__float_as_int(x), 63));
}

// ---- K0: per-image counting sort in ONE kernel (one block per image) ----
__global__ __launch_bounds__(256) void k_sort(const int* __restrict__ gt,
                                              int* __restrict__ counts,
                                              int* __restrict__ starts,
                                              int* __restrict__ sorted) {
    __shared__ int hist[G_];
    __shared__ int scn[G_];
    const int tid = threadIdx.x, b = blockIdx.x;
    hist[tid] = 0;
    __syncthreads();
    const int base = b * N_;
    #pragma unroll 4
    for (int k = 0; k < N_/256; ++k)
        atomicAdd(&hist[gt[base + k*256 + tid]], 1);
    __syncthreads();
    const int c = hist[tid];
    counts[b*G_ + tid] = c;
    scn[tid] = c;
    __syncthreads();
    for (int off = 1; off < G_; off <<= 1) {
        const int v = (tid >= off) ? scn[tid - off] : 0;
        __syncthreads();
        scn[tid] += v;
        __syncthreads();
    }
    const int st = scn[tid] - c;          // exclusive prefix
    starts[b*G_ + tid] = st;
    hist[tid] = st;                        // reuse as cursor
    __syncthreads();
    #pragma unroll 4
    for (int k = 0; k < N_/256; ++k) {
        const int r = k*256 + tid;
        const int g = gt[base + r];
        const int pos = atomicAdd(&hist[g], 1);
        sorted[base + pos] = r;
    }
}

// ---- K1: single-pass fused kernel (one block per (b,g)) ----
// S = sum(p), U = sum(p/|p|) in one read; per-row |p| via DPP wave reduce.
// pull_g = cnt - dot(U,S)/|S|.
__global__ __launch_bounds__(256) void k_fused(const float* __restrict__ pred,
                                               const int* __restrict__ sorted,
                                               const int* __restrict__ starts,
                                               const int* __restrict__ counts,
                                               float* __restrict__ sums,
                                               float* __restrict__ pull_g) {
    __shared__ float sumv[D_];   // 1 KiB
    __shared__ float usum[D_];   // 1 KiB
    __shared__ float redS[4], redU[4];
    const int tid = threadIdx.x, lane = tid & 63, w = tid >> 6;
    const int b = blockIdx.x >> 8, g = blockIdx.x & 255;
    const int start = starts[b*G_ + g], cnt = counts[b*G_ + g];
    const int c = lane * 4;

    if (cnt == 0) {
        if (w == 0) { float4 z = make_float4(0.f,0.f,0.f,0.f);
                      *(float4*)&sums[((size_t)(b*G_+g))*D_ + c] = z; }
        if (tid == 0) pull_g[b*G_+g] = 0.f;
        return;
    }

    sumv[tid] = 0.f;
    usum[tid] = 0.f;
    __syncthreads();

    const float* predb = pred + (size_t)b*N_*D_;
    const int*   sortb = sorted + b*N_ + start;

    float4 acc  = make_float4(0.f,0.f,0.f,0.f);   // sum(p)
    float4 uacc = make_float4(0.f,0.f,0.f,0.f);   // sum(p/|p|)
    int i = w;

    // main loop: 4 rows per wave-iteration, 4 interleaved DPP reduce chains
    for (; i + 12 < cnt; i += 16) {
        const int r0 = sortb[__builtin_amdgcn_readfirstlane(i)];
        const int r1 = sortb[__builtin_amdgcn_readfirstlane(i + 4)];
        const int r2 = sortb[__builtin_amdgcn_readfirstlane(i + 8)];
        const int r3 = sortb[__builtin_amdgcn_readfirstlane(i + 12)];
        const float4 p0 = *(const float4*)&predb[(size_t)r0*D_ + c];
        const float4 p1 = *(const float4*)&predb[(size_t)r1*D_ + c];
        const float4 p2 = *(const float4*)&predb[(size_t)r2*D_ + c];
        const float4 p3 = *(const float4*)&predb[(size_t)r3*D_ + c];
        const float n0 = wave_sum64(p0.x*p0.x + p0.y*p0.y + p0.z*p0.z + p0.w*p0.w);
        const float n1 = wave_sum64(p1.x*p1.x + p1.y*p1.y + p1.z*p1.z + p1.w*p1.w);
        const float n2 = wave_sum64(p2.x*p2.x + p2.y*p2.y + p2.z*p2.z + p2.w*p2.w);
        const float n3 = wave_sum64(p3.x*p3.x + p3.y*p3.y + p3.z*p3.z + p3.w*p3.w);
        const float q0 = __frsqrt_rn(n0);
        const float q1 = __frsqrt_rn(n1);
        const float q2 = __frsqrt_rn(n2);
        const float q3 = __frsqrt_rn(n3);
        acc.x  += (p0.x + p1.x) + (p2.x + p3.x);
        acc.y  += (p0.y + p1.y) + (p2.y + p3.y);
        acc.z  += (p0.z + p1.z) + (p2.z + p3.z);
        acc.w  += (p0.w + p1.w) + (p2.w + p3.w);
        uacc.x += p0.x*q0 + p1.x*q1 + p2.x*q2 + p3.x*q3;
        uacc.y += p0.y*q0 + p1.y*q1 + p2.y*q2 + p3.y*q3;
        uacc.z += p0.z*q0 + p1.z*q1 + p2.z*q2 + p3.z*q3;
        uacc.w += p0.w*q0 + p1.w*q1 + p2.w*q2 + p3.w*q3;
    }
    for (; i < cnt; i += 4) {
        const int r0 = sortb[__builtin_amdgcn_readfirstlane(i)];
        const float4 p0 = *(const float4*)&predb[(size_t)r0*D_ + c];
        const float n0 = wave_sum64(p0.x*p0.x + p0.y*p0.y + p0.z*p0.z + p0.w*p0.w);
        const float q0 = __frsqrt_rn(n0);
        acc.x  += p0.x;    acc.y  += p0.y;    acc.z  += p0.z;    acc.w  += p0.w;
        uacc.x += p0.x*q0; uacc.y += p0.y*q0; uacc.z += p0.z*q0; uacc.w += p0.w*q0;
    }

    atomicAdd(&sumv[c+0], acc.x);
    atomicAdd(&sumv[c+1], acc.y);
    atomicAdd(&sumv[c+2], acc.z);
    atomicAdd(&sumv[c+3], acc.w);
    atomicAdd(&usum[c+0], uacc.x);
    atomicAdd(&usum[c+1], uacc.y);
    atomicAdd(&usum[c+2], uacc.z);
    atomicAdd(&usum[c+3], uacc.w);
    __syncthreads();

    if (w == 0) *(float4*)&sums[((size_t)(b*G_+g))*D_ + c] = *(const float4*)&sumv[c];

    // |S|^2 and dot(U,S) block reduces (DPP within wave, LDS across 4 waves)
    { const float s = sumv[tid], u = usum[tid];
      const float sq = wave_sum64(s * s);
      const float du = wave_sum64(u * s);
      if (lane == 0) { redS[w] = sq; redU[w] = du; } }
    __syncthreads();
    if (tid == 0) {
        const float Ssq   = redS[0] + redS[1] + redS[2] + redS[3];
        const float dotUS = redU[0] + redU[1] + redU[2] + redU[3];
        pull_g[b*G_+g] = (float)cnt - dotUS / sqrtf(Ssq);
    }
}

// ---- K2: per-image push + pull combine -> lossv[b] (plain store) ----
__global__ __launch_bounds__(256) void k_tags(const float* __restrict__ sums,
                                              const int* __restrict__ counts,
                                              const float* __restrict__ pull_g,
                                              float* __restrict__ lossv) {
    const int b = blockIdx.x;
    const int tid = threadIdx.x;
    const int lane = tid & 63;
    const int wave = tid >> 6;
    __shared__ float s_acc[D_];
    __shared__ float redA[256];
    __shared__ float redB[256];

    for (int i = tid; i < D_; i += 256) s_acc[i] = 0.f;
    __syncthreads();

    const int c = lane * 4;
    float4 sl = make_float4(0.f, 0.f, 0.f, 0.f);
    for (int g = wave; g < G_; g += 4) {
        const int cnt = counts[b*G_ + g];
        const float inv = 1.0f / fmaxf((float)cnt, 1.0f);
        const float4 sm = *(const float4*)&sums[((size_t)(b*G_ + g))*D_ + c];
        const float tx = sm.x*inv, tyv = sm.y*inv, tz = sm.z*inv, tw = sm.w*inv;
        const float sq = wave_sum64(tx*tx + tyv*tyv + tz*tz + tw*tw);
        if (cnt > 0) {
            const float it = __frsqrt_rn(sq);
            sl.x += tx*it; sl.y += tyv*it; sl.z += tz*it; sl.w += tw*it;
        }
    }
    atomicAdd(&s_acc[c+0], sl.x);
    atomicAdd(&s_acc[c+1], sl.y);
    atomicAdd(&s_acc[c+2], sl.z);
    atomicAdd(&s_acc[c+3], sl.w);
    __syncthreads();

    // redA: |sum of unit tags|^2 ; redB: obj count
    const int cnt_t = counts[b*G_ + tid];
    const float v = s_acc[tid];
    redA[tid] = v * v;
    redB[tid] = (cnt_t > 0) ? 1.f : 0.f;
    __syncthreads();
    for (int s = 128; s > 0; s >>= 1) {
        if (tid < s) { redA[tid] += redA[tid + s]; redB[tid] += redB[tid + s]; }
        __syncthreads();
    }
    float ssq = 0.f, obj = 0.f;
    if (tid == 0) { ssq = redA[0]; obj = redB[0]; }
    __syncthreads();

    // pull: sum over present groups of pull_g / cnt
    redA[tid] = (cnt_t > 0) ? pull_g[b*G_ + tid] / (float)cnt_t : 0.f;
    __syncthreads();
    for (int s = 128; s > 0; s >>= 1) {
        if (tid < s) redA[tid] += redA[tid + s];
        __syncthreads();
    }
    if (tid == 0) {
        const float push = (obj*obj - 2.f*obj + ssq) / (((obj - 1.f)*obj + EPSF) * 2.f);
        const float pull = redA[0] / (obj + EPSF);
        lossv[b] = (obj > 1.f) ? (push + pull) : 0.f;
    }
}

// ---- K3: final mean (plain store; no d_out memset needed) ----
__global__ void k_out(const float* __restrict__ lossv, float* __restrict__ out) {
    if (threadIdx.x == 0) {
        float t = 0.f;
        #pragma unroll
        for (int b = 0; b < B_; ++b) t += lossv[b];
        out[0] = t * (1.0f / (float)B_);
    }
}

extern "C" void kernel_launch(void* const* d_in, const int* in_sizes, int n_in,
                              void* d_out, int out_size, void* d_ws, size_t ws_size,
                              hipStream_t stream) {
    const float* pred = (const float*)d_in[0];
    const int*   gt   = (const int*)d_in[1];
    float* out = (float*)d_out;

    char* ws = (char*)d_ws;
    const size_t SZ_SUMS = (size_t)B_*G_*D_*sizeof(float);   // 4 MiB
    const size_t SZ_I    = (size_t)B_*G_*sizeof(int);        // 16 KiB each

    float* sums    = (float*)ws;                               ws += SZ_SUMS;
    int*   counts  = (int*)ws;                                 ws += SZ_I;
    int*   starts  = (int*)ws;                                 ws += SZ_I;
    float* pull_g  = (float*)ws;                               ws += SZ_I;
    float* lossv   = (float*)ws;                               ws += 64*sizeof(float);
    int*   sorted  = (int*)ws;                                 // B*N ints = 1 MiB

    k_sort  <<<B_,     256, 0, stream>>>(gt, counts, starts, sorted);
    k_fused <<<B_*G_,  256, 0, stream>>>(pred, sorted, starts, counts, sums, pull_g);
    k_tags  <<<B_,     256, 0, stream>>>(sums, counts, pull_g, lossv);
    k_out   <<<1,       64, 0, stream>>>(lossv, out);
}

// Round 7
// 95.754 us; speedup vs baseline: 5.1992x; 1.4582x over previous
//
#include <hip/hip_runtime.h>

#define B_ 16
#define N_ 16384
#define D_ 256
#define G_ 256
#define EPSF 1e-6f

// ---- DPP wave-64 sum: row_shr 1/2/4/8 + row_bcast15/31, result broadcast via readlane(63).
template <int CTRL>
__device__ __forceinline__ float dpp_add_step(float x) {
    const int y = __builtin_amdgcn_update_dpp(0, __float_as_int(x), CTRL, 0xF, 0xF, false);
    return x + __int_as_float(y);
}
__device__ __forceinline__ float wave_sum64(float x) {
    x = dpp_add_step<0x111>(x);   // row_shr:1
    x = dpp_add_step<0x112>(x);   // row_shr:2
    x = dpp_add_step<0x114>(x);   // row_shr:4
    x = dpp_add_step<0x118>(x);   // row_shr:8
    x = dpp_add_step<0x142>(x);   // row_bcast15
    x = dpp_add_step<0x143>(x);   // row_bcast31 -> lane 63 has wave total
    return __int_as_float(__builtin_amdgcn_readlane(__float_as_int(x), 63));
}

// ---- K0: per-image counting sort, 1024 threads per image ----
__global__ __launch_bounds__(1024) void k_sort(const int* __restrict__ gt,
                                               int* __restrict__ counts,
                                               int* __restrict__ starts,
                                               int* __restrict__ sorted) {
    __shared__ int hist[G_];
    __shared__ int scn[G_];
    const int tid = threadIdx.x, b = blockIdx.x;
    if (tid < G_) hist[tid] = 0;
    __syncthreads();
    const int base = b * N_;
    #pragma unroll
    for (int k = 0; k < N_/1024; ++k)
        atomicAdd(&hist[gt[base + k*1024 + tid]], 1);
    __syncthreads();
    int c = 0;
    if (tid < G_) {
        c = hist[tid];
        counts[b*G_ + tid] = c;
        scn[tid] = c;
    }
    __syncthreads();
    for (int off = 1; off < G_; off <<= 1) {
        int v = 0;
        if (tid < G_ && tid >= off) v = scn[tid - off];
        __syncthreads();
        if (tid < G_) scn[tid] += v;
        __syncthreads();
    }
    if (tid < G_) {
        const int st = scn[tid] - c;          // exclusive prefix
        starts[b*G_ + tid] = st;
        hist[tid] = st;                        // reuse as cursor
    }
    __syncthreads();
    #pragma unroll
    for (int k = 0; k < N_/1024; ++k) {
        const int r = k*1024 + tid;
        const int g = gt[base + r];
        const int pos = atomicAdd(&hist[g], 1);
        sorted[base + pos] = r;
    }
}

// ---- K1: one WAVE per (b,g) group. No LDS, no barriers, no atomics. ----
// S = sum(p), U = sum(p/|p|) in wave-private VGPRs; one read of group rows.
// pull_g = cnt - dot(U,S)/|S|.
__global__ __launch_bounds__(256, 5) void k_fused(const float* __restrict__ pred,
                                                  const int* __restrict__ sorted,
                                                  const int* __restrict__ starts,
                                                  const int* __restrict__ counts,
                                                  float* __restrict__ sums,
                                                  float* __restrict__ pull_g) {
    const int tid = threadIdx.x, lane = tid & 63, w = tid >> 6;
    const int gi = (blockIdx.x << 2) | w;          // = b*G_ + g
    const int b = gi >> 8;
    const int start = starts[gi], cnt = counts[gi];
    const int c = lane * 4;

    if (cnt == 0) {
        float4 z = make_float4(0.f,0.f,0.f,0.f);
        *(float4*)&sums[(size_t)gi*D_ + c] = z;
        if (lane == 0) pull_g[gi] = 0.f;
        return;                                    // wave-level return: no barriers in kernel
    }

    const float* predb = pred + (size_t)b*N_*D_;
    const int*   sortb = sorted + b*N_ + start;

    float4 acc  = make_float4(0.f,0.f,0.f,0.f);    // S (this lane's 4 dims)
    float4 uacc = make_float4(0.f,0.f,0.f,0.f);    // U
    int i = 0;

    if (cnt <= 128) {
        // lane-parallel row-id prefetch into 2 VGPRs; ids via branchless readlane
        const int ids0 = sortb[min(lane, cnt-1)];
        int ids1 = 0;
        if (cnt > 64) ids1 = sortb[min(64 + lane, cnt-1)];
        #define GET2(k) (((k) < 64) ? __builtin_amdgcn_readlane(ids0, (k)) \
                                    : __builtin_amdgcn_readlane(ids1, (k) - 64))
        for (; i + 8 <= cnt; i += 8) {
            const int r0 = GET2(i+0), r1 = GET2(i+1), r2 = GET2(i+2), r3 = GET2(i+3);
            const int r4 = GET2(i+4), r5 = GET2(i+5), r6 = GET2(i+6), r7 = GET2(i+7);
            const float4 p0 = *(const float4*)&predb[(size_t)r0*D_ + c];
            const float4 p1 = *(const float4*)&predb[(size_t)r1*D_ + c];
            const float4 p2 = *(const float4*)&predb[(size_t)r2*D_ + c];
            const float4 p3 = *(const float4*)&predb[(size_t)r3*D_ + c];
            const float4 p4 = *(const float4*)&predb[(size_t)r4*D_ + c];
            const float4 p5 = *(const float4*)&predb[(size_t)r5*D_ + c];
            const float4 p6 = *(const float4*)&predb[(size_t)r6*D_ + c];
            const float4 p7 = *(const float4*)&predb[(size_t)r7*D_ + c];
            float n0 = p0.x*p0.x + p0.y*p0.y + p0.z*p0.z + p0.w*p0.w;
            float n1 = p1.x*p1.x + p1.y*p1.y + p1.z*p1.z + p1.w*p1.w;
            float n2 = p2.x*p2.x + p2.y*p2.y + p2.z*p2.z + p2.w*p2.w;
            float n3 = p3.x*p3.x + p3.y*p3.y + p3.z*p3.z + p3.w*p3.w;
            float n4 = p4.x*p4.x + p4.y*p4.y + p4.z*p4.z + p4.w*p4.w;
            float n5 = p5.x*p5.x + p5.y*p5.y + p5.z*p5.z + p5.w*p5.w;
            float n6 = p6.x*p6.x + p6.y*p6.y + p6.z*p6.z + p6.w*p6.w;
            float n7 = p7.x*p7.x + p7.y*p7.y + p7.z*p7.z + p7.w*p7.w;
            n0 = wave_sum64(n0); n1 = wave_sum64(n1);
            n2 = wave_sum64(n2); n3 = wave_sum64(n3);
            n4 = wave_sum64(n4); n5 = wave_sum64(n5);
            n6 = wave_sum64(n6); n7 = wave_sum64(n7);
            const float q0 = __frsqrt_rn(n0), q1 = __frsqrt_rn(n1);
            const float q2 = __frsqrt_rn(n2), q3 = __frsqrt_rn(n3);
            const float q4 = __frsqrt_rn(n4), q5 = __frsqrt_rn(n5);
            const float q6 = __frsqrt_rn(n6), q7 = __frsqrt_rn(n7);
            acc.x  += ((p0.x + p1.x) + (p2.x + p3.x)) + ((p4.x + p5.x) + (p6.x + p7.x));
            acc.y  += ((p0.y + p1.y) + (p2.y + p3.y)) + ((p4.y + p5.y) + (p6.y + p7.y));
            acc.z  += ((p0.z + p1.z) + (p2.z + p3.z)) + ((p4.z + p5.z) + (p6.z + p7.z));
            acc.w  += ((p0.w + p1.w) + (p2.w + p3.w)) + ((p4.w + p5.w) + (p6.w + p7.w));
            uacc.x += ((p0.x*q0 + p1.x*q1) + (p2.x*q2 + p3.x*q3)) + ((p4.x*q4 + p5.x*q5) + (p6.x*q6 + p7.x*q7));
            uacc.y += ((p0.y*q0 + p1.y*q1) + (p2.y*q2 + p3.y*q3)) + ((p4.y*q4 + p5.y*q5) + (p6.y*q6 + p7.y*q7));
            uacc.z += ((p0.z*q0 + p1.z*q1) + (p2.z*q2 + p3.z*q3)) + ((p4.z*q4 + p5.z*q5) + (p6.z*q6 + p7.z*q7));
            uacc.w += ((p0.w*q0 + p1.w*q1) + (p2.w*q2 + p3.w*q3)) + ((p4.w*q4 + p5.w*q5) + (p6.w*q6 + p7.w*q7));
        }
        for (; i < cnt; ++i) {
            const int r0 = GET2(i);
            const float4 p0 = *(const float4*)&predb[(size_t)r0*D_ + c];
            const float n0 = wave_sum64(p0.x*p0.x + p0.y*p0.y + p0.z*p0.z + p0.w*p0.w);
            const float q0 = __frsqrt_rn(n0);
            acc.x  += p0.x;    acc.y  += p0.y;    acc.z  += p0.z;    acc.w  += p0.w;
            uacc.x += p0.x*q0; uacc.y += p0.y*q0; uacc.z += p0.z*q0; uacc.w += p0.w*q0;
        }
        #undef GET2
    } else {
        // generic fallback (statistically never hit at Poisson(64))
        for (; i < cnt; ++i) {
            const int r0 = sortb[i];
            const float4 p0 = *(const float4*)&predb[(size_t)r0*D_ + c];
            const float n0 = wave_sum64(p0.x*p0.x + p0.y*p0.y + p0.z*p0.z + p0.w*p0.w);
            const float q0 = __frsqrt_rn(n0);
            acc.x  += p0.x;    acc.y  += p0.y;    acc.z  += p0.z;    acc.w  += p0.w;
            uacc.x += p0.x*q0; uacc.y += p0.y*q0; uacc.z += p0.z*q0; uacc.w += p0.w*q0;
        }
    }

    // write S for the push kernel (one coalesced 1 KiB store per wave)
    *(float4*)&sums[(size_t)gi*D_ + c] = acc;

    // |S|^2 and dot(U,S)
    const float ssq = wave_sum64(acc.x*acc.x + acc.y*acc.y + acc.z*acc.z + acc.w*acc.w);
    const float dus = wave_sum64(uacc.x*acc.x + uacc.y*acc.y + uacc.z*acc.z + uacc.w*acc.w);
    if (lane == 0) pull_g[gi] = (float)cnt - dus / sqrtf(ssq);
}

// ---- K2: per-image push + pull combine -> lossv[b] ----
__global__ __launch_bounds__(256) void k_tags(const float* __restrict__ sums,
                                              const int* __restrict__ counts,
                                              const float* __restrict__ pull_g,
                                              float* __restrict__ lossv) {
    const int b = blockIdx.x;
    const int tid = threadIdx.x;
    const int lane = tid & 63;
    const int wave = tid >> 6;
    __shared__ float s_acc[D_];
    __shared__ float redA[256];
    __shared__ float redB[256];

    for (int i = tid; i < D_; i += 256) s_acc[i] = 0.f;
    __syncthreads();

    const int c = lane * 4;
    float4 sl = make_float4(0.f, 0.f, 0.f, 0.f);
    for (int g = wave; g < G_; g += 4) {
        const int cnt = counts[b*G_ + g];
        const float inv = 1.0f / fmaxf((float)cnt, 1.0f);
        const float4 sm = *(const float4*)&sums[((size_t)(b*G_ + g))*D_ + c];
        const float tx = sm.x*inv, tyv = sm.y*inv, tz = sm.z*inv, tw = sm.w*inv;
        const float sq = wave_sum64(tx*tx + tyv*tyv + tz*tz + tw*tw);
        if (cnt > 0) {
            const float it = __frsqrt_rn(sq);
            sl.x += tx*it; sl.y += tyv*it; sl.z += tz*it; sl.w += tw*it;
        }
    }
    atomicAdd(&s_acc[c+0], sl.x);
    atomicAdd(&s_acc[c+1], sl.y);
    atomicAdd(&s_acc[c+2], sl.z);
    atomicAdd(&s_acc[c+3], sl.w);
    __syncthreads();

    const int cnt_t = counts[b*G_ + tid];
    const float v = s_acc[tid];
    redA[tid] = v * v;
    redB[tid] = (cnt_t > 0) ? 1.f : 0.f;
    __syncthreads();
    for (int s = 128; s > 0; s >>= 1) {
        if (tid < s) { redA[tid] += redA[tid + s]; redB[tid] += redB[tid + s]; }
        __syncthreads();
    }
    float ssq = 0.f, obj = 0.f;
    if (tid == 0) { ssq = redA[0]; obj = redB[0]; }
    __syncthreads();

    redA[tid] = (cnt_t > 0) ? pull_g[b*G_ + tid] / (float)cnt_t : 0.f;
    __syncthreads();
    for (int s = 128; s > 0; s >>= 1) {
        if (tid < s) redA[tid] += redA[tid + s];
        __syncthreads();
    }
    if (tid == 0) {
        const float push = (obj*obj - 2.f*obj + ssq) / (((obj - 1.f)*obj + EPSF) * 2.f);
        const float pull = redA[0] / (obj + EPSF);
        lossv[b] = (obj > 1.f) ? (push + pull) : 0.f;
    }
}

// ---- K3: final mean ----
__global__ void k_out(const float* __restrict__ lossv, float* __restrict__ out) {
    if (threadIdx.x == 0) {
        float t = 0.f;
        #pragma unroll
        for (int b = 0; b < B_; ++b) t += lossv[b];
        out[0] = t * (1.0f / (float)B_);
    }
}

extern "C" void kernel_launch(void* const* d_in, const int* in_sizes, int n_in,
                              void* d_out, int out_size, void* d_ws, size_t ws_size,
                              hipStream_t stream) {
    const float* pred = (const float*)d_in[0];
    const int*   gt   = (const int*)d_in[1];
    float* out = (float*)d_out;

    char* ws = (char*)d_ws;
    const size_t SZ_SUMS = (size_t)B_*G_*D_*sizeof(float);   // 4 MiB
    const size_t SZ_I    = (size_t)B_*G_*sizeof(int);        // 16 KiB each

    float* sums    = (float*)ws;                               ws += SZ_SUMS;
    int*   counts  = (int*)ws;                                 ws += SZ_I;
    int*   starts  = (int*)ws;                                 ws += SZ_I;
    float* pull_g  = (float*)ws;                               ws += SZ_I;
    float* lossv   = (float*)ws;                               ws += 64*sizeof(float);
    int*   sorted  = (int*)ws;                                 // B*N ints = 1 MiB

    k_sort  <<<B_,        1024, 0, stream>>>(gt, counts, starts, sorted);
    k_fused <<<B_*G_/4,    256, 0, stream>>>(pred, sorted, starts, counts, sums, pull_g);
    k_tags  <<<B_,         256, 0, stream>>>(sums, counts, pull_g, lossv);
    k_out   <<<1,           64, 0, stream>>>(lossv, out);
}